// Round 11
// baseline (236.679 us; speedup 1.0000x reference)
//
#include <hip/hip_runtime.h>

#define BB 8
#define CC 80
#define HH 128
#define WWW 128
#define KK 32

constexpr int HWc  = HH * WWW;      // 16384
constexpr int CHWc = CC * HWc;      // 1310720
constexpr float RESf   = 1e-4f;
constexpr float PULL_W = 0.1f;
constexpr float PUSH_W = 0.1f;
constexpr float OFF_W  = 1.0f;
constexpr float XCLAMP = 9.210240f; // ln(9999): sigmoid(±XCLAMP) = 1-1e-4 / 1e-4

typedef float f32x4 __attribute__((ext_vector_type(4)));

// ws layout (floats):
// [0..B) tl focal | [B..2B) tl npos | [2B..3B) br focal | [3B..4B) br npos
// [4B..5B) tl offset | [5B..6B) br offset
// [6B .. 6B+B*(K+1)) tl_list | [+B*(K+1)) br_list
// [WS_FLOATS] completion counter (as uint)
constexpr int WS_FLOATS = 6 * BB + 2 * BB * (KK + 1);

constexpr int NSML = 192;    // 12 * BB * 2 small-work blocks (scheduled first)
constexpr int NFOC = 1024;   // 64 * BB * 2 focal blocks (R9's exact geometry)
constexpr int NTOT = NSML + NFOC;

__device__ __forceinline__ void waveReduce2(float& a, float& b) {
#pragma unroll
    for (int off = 32; off; off >>= 1) {
        a += __shfl_down(a, off);
        b += __shfl_down(b, off);
    }
}

__device__ __forceinline__ float waveReduce1(float a) {
#pragma unroll
    for (int off = 32; off; off >>= 1) a += __shfl_down(a, off);
    return a;
}

// Coherent cross-block read: ws is written via device-scope atomicAdd; read
// it through an atomic RMW so the access happens at the coherent point
// (plain loads could hit a stale per-XCD L2 line).
__device__ __forceinline__ float aload(float* p) { return atomicAdd(p, 0.0f); }

// R11 = R9's focal (best measured: 41.6 us, 4.04 TB/s eff; nt evict-first
// loads broke the L2/L3 thrash) + everything fused into ONE dispatch:
//  - blocks [0, NSML): offset smooth-L1 + embed segment-sum (overlaps focal)
//  - blocks [NSML, NTOT): focal, identical to R9 (64 blocks/slice, U=4,
//    MACRO=5, 4 blocks/CU -- R10 proved 8/CU + U=5 regresses to 60 us)
//  - last finishing block runs the final pull/push/total reduction
//    (threadfence + counter; stream had 3 dispatches = ~17 us of tail).
__global__ __launch_bounds__(256) void loss_kernel(
    const float* __restrict__ tl, const float* __restrict__ gtl,
    const float* __restrict__ br, const float* __restrict__ gbr,
    const float* __restrict__ tlo, const float* __restrict__ gtlo,
    const float* __restrict__ bro, const float* __restrict__ gbro,
    const float* __restrict__ tle, const float* __restrict__ bre,
    const int* __restrict__ tpos, const int* __restrict__ bpos,
    const int* __restrict__ gt_obj_mask,
    float* ws, float* out) {
    __shared__ float sred[4], sred2[4];
    __shared__ bool is_last;

    const int bid = blockIdx.x;
    const int t = threadIdx.x;

    if (bid < NSML) {
        // ---------------- small work: offset + gather ----------------
        const int s = bid;
        const int x = s % 12;
        const int b = (s / 12) % BB;
        const int z = s / (12 * BB);
        const int* pos = (z ? bpos : tpos) + (size_t)b * HWc;
        const int4* pos4 = (const int4*)pos;

        if (x < 8) {
            // offset: smooth-L1 over (2,H,W), masked by pos!=0
            const f32x4* pr4 = (const f32x4*)((z ? bro : tlo) + (size_t)b * 2 * HWc);
            const f32x4* gt4 = (const f32x4*)((z ? gbro : gtlo) + (size_t)b * 2 * HWc);
            const int n4 = 2 * HWc / 4;          // 8192
            const int hw4n = HWc / 4;            // 4096 (pow2)
            float sacc = 0.f;
            for (int i = x * 256 + t; i < n4; i += 8 * 256) {
                int hw4 = i & (hw4n - 1);
                f32x4 pv = __builtin_nontemporal_load(pr4 + i);
                f32x4 gv = __builtin_nontemporal_load(gt4 + i);
                int4 pp = pos4[hw4];
                int ms[4] = {pp.x, pp.y, pp.z, pp.w};
#pragma unroll
                for (int j = 0; j < 4; ++j) {
                    float d = fabsf(pv[j] - gv[j]);
                    float l = (d < 1.f) ? 0.5f * d * d : d - 0.5f;
                    sacc += (ms[j] != 0) ? l : 0.f;
                }
            }
            sacc = waveReduce1(sacc);
            if ((t & 63) == 0) sred[t >> 6] = sacc;
            __syncthreads();
            if (t == 0)
                atomicAdd(&ws[4 * BB + z * BB + b],
                          sred[0] + sred[1] + sred[2] + sred[3]);
        } else {
            // gather: segment-sum embeds by pos id
            const f32x4* e4 = (const f32x4*)((z ? bre : tle) + (size_t)b * HWc);
            float* list = ws + 6 * BB + z * BB * (KK + 1) + b * (KK + 1);
            const int n4 = HWc / 4;              // 4096
            for (int i = (x - 8) * 256 + t; i < n4; i += 4 * 256) {
                f32x4 ev = __builtin_nontemporal_load(e4 + i);
                int4 pv = pos4[i];
                if (pv.x) atomicAdd(&list[pv.x], ev[0]);
                if (pv.y) atomicAdd(&list[pv.y], ev[1]);
                if (pv.z) atomicAdd(&list[pv.z], ev[2]);
                if (pv.w) atomicAdd(&list[pv.w], ev[3]);
            }
            __syncthreads();
        }
    } else {
        // ---------------- focal (R9 geometry, verbatim) ----------------
        const int r = bid - NSML;            // 0..1023
        const int x = r & 63;
        const int b = (r >> 6) & 7;
        const int z = r >> 9;
        const f32x4* lg4 = (const f32x4*)((z ? br : tl) + (size_t)b * CHWc);
        const f32x4* gt4 = (const f32x4*)((z ? gbr : gtl) + (size_t)b * CHWc);
        float* lsum = ws + z * 2 * BB;
        float* npos = lsum + BB;

        constexpr int S = 64 * 256;               // 16384 threads in x
        constexpr int U = 4;
        constexpr int MACRO = CHWc / 4 / (U * S); // 5
        const int tid = x * 256 + t;

        float ls = 0.f, np = 0.f;
#pragma unroll 1
        for (int m = 0; m < MACRO; ++m) {
            const int base = m * U * S + tid;
            f32x4 xv[U], gv[U];
#pragma unroll
            for (int u = 0; u < U; ++u) {
                xv[u] = __builtin_nontemporal_load(lg4 + base + u * S);
                gv[u] = __builtin_nontemporal_load(gt4 + base + u * S);
            }
#pragma unroll
            for (int u = 0; u < U; ++u) {
#pragma unroll
                for (int j = 0; j < 4; ++j) {
                    float xx = xv[u][j], g = gv[u][j];
                    // clamp x <=> clip(sigmoid(x), 1e-4, 1-1e-4)
                    float xc = fminf(fmaxf(xx, -XCLAMP), XCLAMP);
                    float e = __expf(xc);
                    float rr = __builtin_amdgcn_rcpf(1.f + e); // rr = 1-p
                    float p = e * rr;
                    float logq = __logf(rr);     // log(1-p)
                    float logp = xc + logq;      // log(p)
                    bool pos = (g == 1.0f);
                    float om = 1.f - g;
                    float om2 = om * om;
                    float v = pos ? rr * rr * logp
                                  : om2 * om2 * p * p * logq;
                    ls += v;
                    np += pos ? 1.f : 0.f;
                }
            }
        }
        waveReduce2(ls, np);
        if ((t & 63) == 0) { sred[t >> 6] = ls; sred2[t >> 6] = np; }
        __syncthreads();
        if (t == 0) {
            atomicAdd(&lsum[b], sred[0] + sred[1] + sred[2] + sred[3]);
            atomicAdd(&npos[b], sred2[0] + sred2[1] + sred2[2] + sred2[3]);
        }
    }

    // ---------------- completion counter; last block -> final ----------------
    __threadfence();           // every thread: order its ws atomics
    __syncthreads();           // all fences in block done
    if (t == 0) {
        unsigned* cnt = (unsigned*)(ws + WS_FLOATS);
        unsigned old = atomicAdd(cnt, 1u);
        is_last = (old == (unsigned)(NTOT - 1));
    }
    __syncthreads();
    if (!is_last) return;

    // ================= final reduction (one block) =================
    __shared__ float tls[BB * (KK + 1)], brs[BB * (KK + 1)], mns[BB * (KK + 1)];
    __shared__ float objf[BB];
    __threadfence();
    if (t < BB) objf[t] = (float)gt_obj_mask[t];
    float* wtl = ws + 6 * BB;
    float* wbr = wtl + BB * (KK + 1);
    for (int i = t; i < BB * (KK + 1); i += 256) {
        int k = i % (KK + 1);
        float a = (k == 0) ? 0.f : aload(&wtl[i]);
        float c = (k == 0) ? 0.f : aload(&wbr[i]);
        tls[i] = a; brs[i] = c; mns[i] = 0.5f * (a + c);
    }
    __syncthreads();

    float acc = 0.f;
    // pull
    for (int i = t; i < BB * (KK + 1); i += 256) {
        int b = i / (KK + 1);
        float m = mns[i];
        float d1 = tls[i] - m, d2 = brs[i] - m;
        acc += PULL_W * (d1 * d1 + d2 * d2) / (objf[b] + RESf);
    }
    // push: D_ij = relu(1-|m_i-m_j|), i,j in [1..K]
    for (int i = t; i < BB * KK * KK; i += 256) {
        int b = i / (KK * KK);
        int r = i % (KK * KK);
        int ii = r / KK, jj = r % KK;
        float mi = mns[b * (KK + 1) + 1 + ii];
        float mj = mns[b * (KK + 1) + 1 + jj];
        float d = 1.f - fabsf(mi - mj);
        float D = d > 0.f ? d : 0.f;
        acc += PUSH_W * D / (objf[b] * (objf[b] - 1.f) + RESf);
    }
    // per-batch scalar terms
    for (int b = t; b < BB; b += 256) {
        float of = objf[b];
        acc += -aload(&ws[b]) / aload(&ws[BB + b]);           // tl focal
        acc += -aload(&ws[2 * BB + b]) / aload(&ws[3 * BB + b]); // br focal
        acc += OFF_W * aload(&ws[4 * BB + b]) / (of + RESf);  // tl offset
        acc += OFF_W * aload(&ws[5 * BB + b]) / (of + RESf);  // br offset
        acc += -PUSH_W * of / (of * (of - 1.f) + RESf);       // "- objf"
    }

    acc = waveReduce1(acc);
    __syncthreads();   // reuse sred safely
    if ((t & 63) == 0) sred[t >> 6] = acc;
    __syncthreads();
    if (t == 0) out[0] = (sred[0] + sred[1] + sred[2] + sred[3]) / (float)BB;
}

extern "C" void kernel_launch(void* const* d_in, const int* in_sizes, int n_in,
                              void* d_out, int out_size, void* d_ws, size_t ws_size,
                              hipStream_t stream) {
    const float* tl_heats      = (const float*)d_in[0];
    const float* tl_embeds     = (const float*)d_in[1];
    const float* tl_offsets    = (const float*)d_in[2];
    const float* br_heats      = (const float*)d_in[3];
    const float* br_embeds     = (const float*)d_in[4];
    const float* br_offsets    = (const float*)d_in[5];
    const float* gt_tl_heats   = (const float*)d_in[6];
    const float* gt_br_heats   = (const float*)d_in[7];
    const float* gt_tl_offsets = (const float*)d_in[8];
    const float* gt_br_offsets = (const float*)d_in[9];
    const int*   gt_tl_pos     = (const int*)d_in[10];
    const int*   gt_br_pos     = (const int*)d_in[11];
    const int*   gt_obj_mask   = (const int*)d_in[12];
    float* out = (float*)d_out;
    float* ws  = (float*)d_ws;

    hipMemsetAsync(ws, 0, (WS_FLOATS + 1) * sizeof(float), stream);

    loss_kernel<<<dim3(NTOT), 256, 0, stream>>>(
        tl_heats, gt_tl_heats, br_heats, gt_br_heats,
        tl_offsets, gt_tl_offsets, br_offsets, gt_br_offsets,
        tl_embeds, br_embeds, gt_tl_pos, gt_br_pos,
        gt_obj_mask, ws, out);
}

// Round 12
// 53.040 us; speedup vs baseline: 4.4622x; 4.4622x over previous
//
#include <hip/hip_runtime.h>

#define BB 8
#define CC 80
#define HH 128
#define WWW 128
#define KK 32

constexpr int HWc  = HH * WWW;      // 16384
constexpr int CHWc = CC * HWc;      // 1310720
constexpr float RESf   = 1e-4f;
constexpr float PULL_W = 0.1f;
constexpr float PUSH_W = 0.1f;
constexpr float OFF_W  = 1.0f;
constexpr float XCLAMP = 9.210240f; // ln(9999): sigmoid(±XCLAMP) = 1-1e-4 / 1e-4

typedef float f32x4 __attribute__((ext_vector_type(4)));

// ws layout (floats):
// [0..B) tl focal | [B..2B) tl npos | [2B..3B) br focal | [3B..4B) br npos
// [4B..5B) tl offset | [5B..6B) br offset
// [6B .. 6B+B*(K+1)) tl_list | [+B*(K+1)) br_list
// [WS_FLOATS] completion counter (as uint)
constexpr int WS_FLOATS = 6 * BB + 2 * BB * (KK + 1);

constexpr int NSML = 192;    // small-work blocks (scheduled first, overlap focal)
constexpr int NFOC = 1024;   // focal blocks (R9's exact geometry: 41.6 us)
constexpr int NTOT = NSML + NFOC;

__device__ __forceinline__ void waveReduce2(float& a, float& b) {
#pragma unroll
    for (int off = 32; off; off >>= 1) {
        a += __shfl_down(a, off);
        b += __shfl_down(b, off);
    }
}

__device__ __forceinline__ float waveReduce1(float a) {
#pragma unroll
    for (int off = 32; off; off >>= 1) a += __shfl_down(a, off);
    return a;
}

// Coherent cross-block read: all ws producers are device-scope atomicAdd;
// reading via atomic RMW hits the same coherent point (no fence needed).
__device__ __forceinline__ float aload(float* p) { return atomicAdd(p, 0.0f); }

// R12 = R11 minus the fence storm. R11's __threadfence() per WAVE emitted
// device-scope L2 writeback/invalidate (non-coherent XCD L2s) -> ~190 us of
// serialized cache maintenance (230 us total). All cross-block traffic is
// atomicAdd at the coherent point, so the only ordering required is
// "this wave's atomics completed" = s_waitcnt vmcnt(0) (cheap, per-wave),
// then block-level syncthreads, then one counter bump per block.
__global__ __launch_bounds__(256) void loss_kernel(
    const float* __restrict__ tl, const float* __restrict__ gtl,
    const float* __restrict__ br, const float* __restrict__ gbr,
    const float* __restrict__ tlo, const float* __restrict__ gtlo,
    const float* __restrict__ bro, const float* __restrict__ gbro,
    const float* __restrict__ tle, const float* __restrict__ bre,
    const int* __restrict__ tpos, const int* __restrict__ bpos,
    const int* __restrict__ gt_obj_mask,
    float* ws, float* out) {
    __shared__ float sred[4], sred2[4];
    __shared__ bool is_last;

    const int bid = blockIdx.x;
    const int t = threadIdx.x;

    if (bid < NSML) {
        // ---------------- small work: offset + gather ----------------
        const int x = bid % 12;
        const int b = (bid / 12) % BB;
        const int z = bid / (12 * BB);
        const int* pos = (z ? bpos : tpos) + (size_t)b * HWc;
        const int4* pos4 = (const int4*)pos;

        if (x < 8) {
            // offset: smooth-L1 over (2,H,W), masked by pos!=0
            const f32x4* pr4 = (const f32x4*)((z ? bro : tlo) + (size_t)b * 2 * HWc);
            const f32x4* gt4 = (const f32x4*)((z ? gbro : gtlo) + (size_t)b * 2 * HWc);
            const int n4 = 2 * HWc / 4;          // 8192
            const int hw4n = HWc / 4;            // 4096 (pow2)
            float sacc = 0.f;
            for (int i = x * 256 + t; i < n4; i += 8 * 256) {
                int hw4 = i & (hw4n - 1);
                f32x4 pv = __builtin_nontemporal_load(pr4 + i);
                f32x4 gv = __builtin_nontemporal_load(gt4 + i);
                int4 pp = pos4[hw4];
                int ms[4] = {pp.x, pp.y, pp.z, pp.w};
#pragma unroll
                for (int j = 0; j < 4; ++j) {
                    float d = fabsf(pv[j] - gv[j]);
                    float l = (d < 1.f) ? 0.5f * d * d : d - 0.5f;
                    sacc += (ms[j] != 0) ? l : 0.f;
                }
            }
            sacc = waveReduce1(sacc);
            if ((t & 63) == 0) sred[t >> 6] = sacc;
            __syncthreads();
            if (t == 0)
                atomicAdd(&ws[4 * BB + z * BB + b],
                          sred[0] + sred[1] + sred[2] + sred[3]);
        } else {
            // gather: segment-sum embeds by pos id
            const f32x4* e4 = (const f32x4*)((z ? bre : tle) + (size_t)b * HWc);
            float* list = ws + 6 * BB + z * BB * (KK + 1) + b * (KK + 1);
            const int n4 = HWc / 4;              // 4096
            for (int i = (x - 8) * 256 + t; i < n4; i += 4 * 256) {
                f32x4 ev = __builtin_nontemporal_load(e4 + i);
                int4 pv = pos4[i];
                if (pv.x) atomicAdd(&list[pv.x], ev[0]);
                if (pv.y) atomicAdd(&list[pv.y], ev[1]);
                if (pv.z) atomicAdd(&list[pv.z], ev[2]);
                if (pv.w) atomicAdd(&list[pv.w], ev[3]);
            }
        }
    } else {
        // ---------------- focal (R9 geometry, verbatim) ----------------
        const int r = bid - NSML;            // 0..1023
        const int x = r & 63;
        const int b = (r >> 6) & 7;
        const int z = r >> 9;
        const f32x4* lg4 = (const f32x4*)((z ? br : tl) + (size_t)b * CHWc);
        const f32x4* gt4 = (const f32x4*)((z ? gbr : gtl) + (size_t)b * CHWc);
        float* lsum = ws + z * 2 * BB;
        float* npos = lsum + BB;

        constexpr int S = 64 * 256;               // 16384 threads per slice
        constexpr int U = 4;
        constexpr int MACRO = CHWc / 4 / (U * S); // 5
        const int tid = x * 256 + t;

        float ls = 0.f, np = 0.f;
#pragma unroll 1
        for (int m = 0; m < MACRO; ++m) {
            const int base = m * U * S + tid;
            f32x4 xv[U], gv[U];
#pragma unroll
            for (int u = 0; u < U; ++u) {
                xv[u] = __builtin_nontemporal_load(lg4 + base + u * S);
                gv[u] = __builtin_nontemporal_load(gt4 + base + u * S);
            }
#pragma unroll
            for (int u = 0; u < U; ++u) {
#pragma unroll
                for (int j = 0; j < 4; ++j) {
                    float xx = xv[u][j], g = gv[u][j];
                    // clamp x <=> clip(sigmoid(x), 1e-4, 1-1e-4)
                    float xc = fminf(fmaxf(xx, -XCLAMP), XCLAMP);
                    float e = __expf(xc);
                    float rr = __builtin_amdgcn_rcpf(1.f + e); // rr = 1-p
                    float p = e * rr;
                    float logq = __logf(rr);     // log(1-p)
                    float logp = xc + logq;      // log(p)
                    bool pos = (g == 1.0f);
                    float om = 1.f - g;
                    float om2 = om * om;
                    float v = pos ? rr * rr * logp
                                  : om2 * om2 * p * p * logq;
                    ls += v;
                    np += pos ? 1.f : 0.f;
                }
            }
        }
        waveReduce2(ls, np);
        if ((t & 63) == 0) { sred[t >> 6] = ls; sred2[t >> 6] = np; }
        __syncthreads();
        if (t == 0) {
            atomicAdd(&lsum[b], sred[0] + sred[1] + sred[2] + sred[3]);
            atomicAdd(&npos[b], sred2[0] + sred2[1] + sred2[2] + sred2[3]);
        }
    }

    // ---- completion protocol: per-wave drain (NO cache-maintenance fence) ----
    asm volatile("s_waitcnt vmcnt(0)" ::: "memory"); // own atomics completed
    __syncthreads();                                 // all waves in block done
    if (t == 0) {
        unsigned* cnt = (unsigned*)(ws + WS_FLOATS);
        unsigned old = atomicAdd(cnt, 1u);
        is_last = (old == (unsigned)(NTOT - 1));
    }
    __syncthreads();
    if (!is_last) return;

    // ================= final reduction (one block) =================
    __shared__ float tls[BB * (KK + 1)], brs[BB * (KK + 1)], mns[BB * (KK + 1)];
    __shared__ float objf[BB];
    if (t < BB) objf[t] = (float)gt_obj_mask[t];
    float* wtl = ws + 6 * BB;
    float* wbr = wtl + BB * (KK + 1);
    for (int i = t; i < BB * (KK + 1); i += 256) {
        int k = i % (KK + 1);
        float a = (k == 0) ? 0.f : aload(&wtl[i]);
        float c = (k == 0) ? 0.f : aload(&wbr[i]);
        tls[i] = a; brs[i] = c; mns[i] = 0.5f * (a + c);
    }
    __syncthreads();

    float acc = 0.f;
    // pull
    for (int i = t; i < BB * (KK + 1); i += 256) {
        int b = i / (KK + 1);
        float m = mns[i];
        float d1 = tls[i] - m, d2 = brs[i] - m;
        acc += PULL_W * (d1 * d1 + d2 * d2) / (objf[b] + RESf);
    }
    // push: D_ij = relu(1-|m_i-m_j|), i,j in [1..K]
    for (int i = t; i < BB * KK * KK; i += 256) {
        int b = i / (KK * KK);
        int r = i % (KK * KK);
        int ii = r / KK, jj = r % KK;
        float mi = mns[b * (KK + 1) + 1 + ii];
        float mj = mns[b * (KK + 1) + 1 + jj];
        float d = 1.f - fabsf(mi - mj);
        float D = d > 0.f ? d : 0.f;
        acc += PUSH_W * D / (objf[b] * (objf[b] - 1.f) + RESf);
    }
    // per-batch scalar terms
    for (int b = t; b < BB; b += 256) {
        float of = objf[b];
        acc += -aload(&ws[b]) / aload(&ws[BB + b]);              // tl focal
        acc += -aload(&ws[2 * BB + b]) / aload(&ws[3 * BB + b]); // br focal
        acc += OFF_W * aload(&ws[4 * BB + b]) / (of + RESf);     // tl offset
        acc += OFF_W * aload(&ws[5 * BB + b]) / (of + RESf);     // br offset
        acc += -PUSH_W * of / (of * (of - 1.f) + RESf);          // "- objf"
    }

    acc = waveReduce1(acc);
    __syncthreads();   // safe reuse of sred
    if ((t & 63) == 0) sred[t >> 6] = acc;
    __syncthreads();
    if (t == 0) out[0] = (sred[0] + sred[1] + sred[2] + sred[3]) / (float)BB;
}

extern "C" void kernel_launch(void* const* d_in, const int* in_sizes, int n_in,
                              void* d_out, int out_size, void* d_ws, size_t ws_size,
                              hipStream_t stream) {
    const float* tl_heats      = (const float*)d_in[0];
    const float* tl_embeds     = (const float*)d_in[1];
    const float* tl_offsets    = (const float*)d_in[2];
    const float* br_heats      = (const float*)d_in[3];
    const float* br_embeds     = (const float*)d_in[4];
    const float* br_offsets    = (const float*)d_in[5];
    const float* gt_tl_heats   = (const float*)d_in[6];
    const float* gt_br_heats   = (const float*)d_in[7];
    const float* gt_tl_offsets = (const float*)d_in[8];
    const float* gt_br_offsets = (const float*)d_in[9];
    const int*   gt_tl_pos     = (const int*)d_in[10];
    const int*   gt_br_pos     = (const int*)d_in[11];
    const int*   gt_obj_mask   = (const int*)d_in[12];
    float* out = (float*)d_out;
    float* ws  = (float*)d_ws;

    hipMemsetAsync(ws, 0, (WS_FLOATS + 1) * sizeof(float), stream);

    loss_kernel<<<dim3(NTOT), 256, 0, stream>>>(
        tl_heats, gt_tl_heats, br_heats, gt_br_heats,
        tl_offsets, gt_tl_offsets, br_offsets, gt_br_offsets,
        tl_embeds, br_embeds, gt_tl_pos, gt_br_pos,
        gt_obj_mask, ws, out);
}